// Round 11
// baseline (246.303 us; speedup 1.0000x reference)
//
#include <hip/hip_runtime.h>
#include <float.h>

typedef __attribute__((ext_vector_type(8))) short short8;   // 8 bf16 (4 VGPRs)
typedef __attribute__((ext_vector_type(4))) float f32x4;    // MFMA C/D
typedef unsigned short u16;
typedef unsigned long long u64;

// ---------------- workspace layout (float offsets), lifetime-aliased ----------------
static constexpr size_t OFF_W     = 0;          // weight hi/lo planes (persistent)
static constexpr size_t OFF_YZ    = 131072;     // y fp32 [8*2048][64]
static constexpr size_t OFF_Zf    = 1179648;    // z fp32
static constexpr size_t OFF_FEATR = 2228224;    // xt planes -> knn part (u64)
static constexpr size_t OFF_FIN   = 6422528;    // h2t hi/lo
static constexpr size_t OFF_XX    = 9568256;    // 16384
static constexpr size_t OFF_G     = 9584640;    // gmax partials 8*64*64 = 32768
static constexpr size_t OFF_G4    = 9617408;    // g4 fp32 8*256 = 2048
static constexpr size_t WS_FLOATS = 9652736;    // ~38.6 MB

// weight sub-offsets (u16 elements within each plane)
static constexpr size_t WO_DUP = 0;       // 256x128
static constexpr size_t WO_C1  = 32768;   // 64x128
static constexpr size_t WO_2A  = 40960;   // 64x128
static constexpr size_t WO_2B  = 49152;   // 64x64
static constexpr size_t WO_2C  = 53248;   // 64x64
static constexpr size_t WO_4A  = 57344;   // 256x192

// async 16B global->LDS (wave-uniform base + lane*16)
__device__ __forceinline__ void gl_lds16(const void* g, void* l) {
    __builtin_amdgcn_global_load_lds(
        (const __attribute__((address_space(1))) void*)g,
        (__attribute__((address_space(3))) void*)l, 16, 0, 0);
}

__device__ __forceinline__ u16 f2bf(float x) {
    union { float f; unsigned int u; } v; v.f = x;
    unsigned int r = v.u + 0x7fffu + ((v.u >> 16) & 1u);
    return (u16)(r >> 16);
}
__device__ __forceinline__ float bf2f(u16 h) {
    union { unsigned int u; float f; } v; v.u = ((unsigned int)h) << 16;
    return v.f;
}
__device__ __forceinline__ void split2(float x, u16& h, u16& l) {
    h = f2bf(x);
    l = f2bf(x - bf2f(h));
}

// monotone float->uint map (exact, no NaNs here)
__device__ __forceinline__ unsigned int fmap(float f) {
    unsigned int u = __float_as_uint(f);
    return u ^ ((unsigned int)((int)u >> 31) | 0x80000000u);
}
// key: high32 = mapped value, low32 = 2047-m  (desc value, asc index)
__device__ __forceinline__ u64 mkkey(float f, int m) {
    return ((u64)fmap(f) << 32) | (unsigned int)(2047 - m);
}
// sorted-desc top-4 insert on u64 keys
static __device__ __forceinline__ void ins4k(u64 k, u64 bk[4])
{
#pragma unroll
    for (int s = 0; s < 4; ++s) {
        bool better = k > bk[s];
        u64 t = bk[s];
        bk[s] = better ? k : bk[s];
        k = better ? t : k;
    }
}

// =================================================================
// PREP: wsplit (blocks 0..415) + tsplit_x (blocks 416..671)
// =================================================================
__global__ __launch_bounds__(256) void prep(
    const float* __restrict__ W_dup, const float* __restrict__ W_c1,
    const float* __restrict__ W2a, const float* __restrict__ W2b,
    const float* __restrict__ W2c, const float* __restrict__ W4a,
    const float* __restrict__ x,
    u16* __restrict__ whi, u16* __restrict__ wlo,
    u16* __restrict__ xthi, u16* __restrict__ xtlo)
{
    __shared__ float tile[64][65];
    if (blockIdx.x < 416) {
        int t = blockIdx.x * 256 + threadIdx.x;   // 106,496
        float v;
        if      (t < 40960) v = (t < 32768) ? W_dup[t] : W_c1[t - 32768];
        else if (t < 53248) v = (t < 49152) ? W2a[t - 40960] : W2b[t - 49152];
        else                v = (t < 57344) ? W2c[t - 53248] : W4a[t - 57344];
        u16 h, l; split2(v, h, l);
        whi[t] = h; wlo[t] = l;
    } else {
        const int bb = blockIdx.x - 416;           // 0..255
        const int n0 = (bb & 15) * 64;
        const int c0 = ((bb >> 4) & 1) * 64;
        const int b  = bb >> 5;
        const int t  = threadIdx.x;
        const float* xb = x + ((size_t)b * 128 + c0) * 1024;
#pragma unroll
        for (int i = 0; i < 16; ++i) {
            int c = i * 4 + (t >> 6), n = t & 63;
            tile[c][n] = xb[(size_t)c * 1024 + n0 + n];
        }
        __syncthreads();
#pragma unroll
        for (int i = 0; i < 16; ++i) {
            int n = i * 4 + (t >> 6), c = t & 63;
            u16 h, l; split2(tile[c][n], h, l);
            const size_t o = ((size_t)b * 1024 + n0 + n) * 128 + c0 + c;
            xthi[o] = h; xtlo[o] = l;
        }
    }
}

// =================================================================
// BACKBONE: conv1(+reshape) -> h2(+xx,+gmax partials) -> y,z
// 512 threads = 8 waves; grid (64 nblocks, 8 b) = 512. (unchanged r10)
// =================================================================
__global__ __launch_bounds__(512) void backbone(
    const u16* __restrict__ xthi, const u16* __restrict__ xtlo,
    const u16* __restrict__ whi, const u16* __restrict__ wlo,
    const float* __restrict__ s_dup, const float* __restrict__ b_dup,
    const float* __restrict__ s_c1, const float* __restrict__ b_c1,
    u16* __restrict__ h2thi, u16* __restrict__ h2tlo,
    float* __restrict__ xxb, float* __restrict__ gp,
    float* __restrict__ y, float* __restrict__ z)
{
    const int t = threadIdx.x;
    const int wu = t >> 6;              // 0..7
    const int lane = t & 63;
    const int j = lane & 15, q = lane >> 4;
    const int nb = blockIdx.x;          // 0..63
    const int b  = blockIdx.y;          // 0..7
    const int n0 = nb * 16;

    __shared__ __align__(16) u16 h1h[32 * 136], h1l[32 * 136];
    __shared__ __align__(16) u16 h2h[32 * 72],  h2l[32 * 72];
    __shared__ float xxp[2][4][16];
    __shared__ float gpart[2][64];

    {
        const size_t arow = ((size_t)b * 1024 + n0 + j) * 128;
        short8 ahv[4], alv[4];
#pragma unroll
        for (int ks = 0; ks < 4; ++ks) {
            ahv[ks] = *(const short8*)(xthi + arow + q * 8 + ks * 32);
            alv[ks] = *(const short8*)(xtlo + arow + q * 8 + ks * 32);
        }
        const u16* wdh = whi + WO_DUP;
        const u16* wdl = wlo + WO_DUP;
#pragma unroll
        for (int ci = 0; ci < 2; ++ci) {
            const int ctile = wu * 2 + ci;
            const int o = ctile * 16 + j;
            f32x4 acc = (f32x4){0.f, 0.f, 0.f, 0.f};
#pragma unroll
            for (int ks = 0; ks < 4; ++ks) {
                short8 bh = *(const short8*)(wdh + (size_t)o * 128 + q * 8 + ks * 32);
                short8 bl = *(const short8*)(wdl + (size_t)o * 128 + q * 8 + ks * 32);
                acc = __builtin_amdgcn_mfma_f32_16x16x32_bf16(ahv[ks], bh, acc, 0, 0, 0);
                acc = __builtin_amdgcn_mfma_f32_16x16x32_bf16(ahv[ks], bl, acc, 0, 0, 0);
                acc = __builtin_amdgcn_mfma_f32_16x16x32_bf16(alv[ks], bh, acc, 0, 0, 0);
            }
            const float sc = s_dup[o], bi = b_dup[o];
            const int lrbase = (j & 1) * 16;
            const int col = ctile * 8 + (j >> 1);
#pragma unroll
            for (int r = 0; r < 4; ++r) {
                float v = fmaxf(acc[r] * sc + bi, 0.f);
                u16 h, l; split2(v, h, l);
                const int lr = lrbase + q * 4 + r;
                h1h[lr * 136 + col] = h;
                h1l[lr * 136 + col] = l;
            }
        }
    }
    __syncthreads();

    {
        const int g = wu >> 2, cq = wu & 3;
        short8 ahv[4], alv[4];
#pragma unroll
        for (int ks = 0; ks < 4; ++ks) {
            ahv[ks] = *(const short8*)&h1h[(g * 16 + j) * 136 + q * 8 + ks * 32];
            alv[ks] = *(const short8*)&h1l[(g * 16 + j) * 136 + q * 8 + ks * 32];
        }
        const u16* wch = whi + WO_C1;
        const u16* wcl = wlo + WO_C1;
        const int o = cq * 16 + j;
        f32x4 acc = (f32x4){0.f, 0.f, 0.f, 0.f};
#pragma unroll
        for (int ks = 0; ks < 4; ++ks) {
            short8 bh = *(const short8*)(wch + (size_t)o * 128 + q * 8 + ks * 32);
            short8 bl = *(const short8*)(wcl + (size_t)o * 128 + q * 8 + ks * 32);
            acc = __builtin_amdgcn_mfma_f32_16x16x32_bf16(ahv[ks], bh, acc, 0, 0, 0);
            acc = __builtin_amdgcn_mfma_f32_16x16x32_bf16(ahv[ks], bl, acc, 0, 0, 0);
            acc = __builtin_amdgcn_mfma_f32_16x16x32_bf16(alv[ks], bh, acc, 0, 0, 0);
        }
        const float sc = s_c1[o], bi = b_c1[o];
        float sq[4];
        float cm = -FLT_MAX;
#pragma unroll
        for (int r = 0; r < 4; ++r) {
            float v = fmaxf(acc[r] * sc + bi, 0.f);
            sq[r] = v * v;
            cm = fmaxf(cm, v);
            u16 h, l; split2(v, h, l);
            const size_t R = (size_t)b * 2048 + g * 1024 + n0 + q * 4 + r;
            h2thi[R * 64 + o] = h;
            h2tlo[R * 64 + o] = l;
            const int lr = g * 16 + q * 4 + r;
            h2h[lr * 72 + o] = h;
            h2l[lr * 72 + o] = l;
        }
#pragma unroll
        for (int r = 0; r < 4; ++r) {
#pragma unroll
            for (int mask = 1; mask < 16; mask <<= 1)
                sq[r] += __shfl_xor(sq[r], mask, 64);
        }
        if (j == 0) {
#pragma unroll
            for (int r = 0; r < 4; ++r) xxp[g][cq][q * 4 + r] = sq[r];
        }
        cm = fmaxf(cm, __shfl_xor(cm, 16, 64));
        cm = fmaxf(cm, __shfl_xor(cm, 32, 64));
        if (q == 0) gpart[g][cq * 16 + j] = cm;
    }
    __syncthreads();

    if (t < 32) {
        const int g = t >> 4, i = t & 15;
        xxb[(size_t)b * 2048 + g * 1024 + n0 + i] =
            (xxp[g][0][i] + xxp[g][1][i]) + (xxp[g][2][i] + xxp[g][3][i]);
    }
    if (t >= 64 && t < 128) {
        const int c = t - 64;
        gp[((size_t)b * 64 + nb) * 64 + c] = fmaxf(gpart[0][c], gpart[1][c]);
    }

    {
        const int g = wu >> 2, half = (wu >> 1) & 1, cg = wu & 1;
        short8 ahv[2], alv[2];
#pragma unroll
        for (int ks = 0; ks < 2; ++ks) {
            ahv[ks] = *(const short8*)&h2h[(g * 16 + j) * 72 + q * 8 + ks * 32];
            alv[ks] = *(const short8*)&h2l[(g * 16 + j) * 72 + q * 8 + ks * 32];
        }
        const u16* w2h = whi + WO_2A;
        const u16* w2l = wlo + WO_2A;
        float* dst = half ? z : y;
#pragma unroll
        for (int ci = 0; ci < 2; ++ci) {
            const int o = (cg * 2 + ci) * 16 + j;
            f32x4 acc = (f32x4){0.f, 0.f, 0.f, 0.f};
#pragma unroll
            for (int ks = 0; ks < 2; ++ks) {
                short8 bh = *(const short8*)(w2h + (size_t)o * 128 + half * 64 + q * 8 + ks * 32);
                short8 bl = *(const short8*)(w2l + (size_t)o * 128 + half * 64 + q * 8 + ks * 32);
                acc = __builtin_amdgcn_mfma_f32_16x16x32_bf16(ahv[ks], bh, acc, 0, 0, 0);
                acc = __builtin_amdgcn_mfma_f32_16x16x32_bf16(ahv[ks], bl, acc, 0, 0, 0);
                acc = __builtin_amdgcn_mfma_f32_16x16x32_bf16(alv[ks], bh, acc, 0, 0, 0);
            }
#pragma unroll
            for (int r = 0; r < 4; ++r) {
                const size_t R = (size_t)b * 2048 + g * 1024 + n0 + q * 4 + r;
                dst[R * 64 + o] = acc[r];
            }
        }
    }
}

// =================================================================
// kNN: split-bf16 MFMA, m-HALVES, u64 keys, 2-WAVE blocks, 32-m tiles.
// Grid (64 rowblocks of 32, 2 mh, 8 b) = 1024 blocks; LDS 16.5 KB ->
// ~9 blocks/CU = 18 waves/CU (was 8). Selection semantics identical.
// =================================================================
struct __align__(16) KBuf {
    u16 hi[2048];   // 8 chunks x 32 m x 8 bf16
    u16 lo[2048];
    float xm[32];
};

__global__ __launch_bounds__(128) void knn_topk(const u16* __restrict__ thi,
                                                const u16* __restrict__ tlo,
                                                const float* __restrict__ xx,
                                                u64* __restrict__ part)
{
    const int b    = blockIdx.z;
    const int mh   = blockIdx.y;
    const int t    = threadIdx.x;
    const int wu   = __builtin_amdgcn_readfirstlane(t >> 6);   // 0..1
    const int lane = t & 63;
    const int j    = lane & 15;
    const int q    = lane >> 4;
    const int nrow0 = blockIdx.x * 32 + wu * 16;

    const u16* th = thi + (size_t)b * 2048 * 64;
    const u16* tl = tlo + (size_t)b * 2048 * 64;
    const float* xb = xx + (size_t)b * 2048;

    __shared__ KBuf sb[2];

    const size_t arow = (size_t)(nrow0 + j) * 64;
    short8 ah0 = *(const short8*)(th + arow + q * 8);
    short8 ah1 = *(const short8*)(th + arow + 32 + q * 8);
    short8 al0 = *(const short8*)(tl + arow + q * 8);
    short8 al1 = *(const short8*)(tl + arow + 32 + q * 8);

    u64 bk[4][4];
#pragma unroll
    for (int r = 0; r < 4; ++r)
#pragma unroll
        for (int s = 0; s < 4; ++s) bk[r][s] = 0ull;

    const int mbeg = mh * 1024;

    // stage 32m x 64c tile, chunk-major (slot s = chunk*32 + m), 2 issues/wave/plane
#define KNN_STAGE(BUF, M0)                                                        \
    {                                                                             \
        _Pragma("unroll")                                                         \
        for (int ii = 0; ii < 2; ++ii) {                                          \
            const int s = (wu * 2 + ii) * 64 + lane;                              \
            const int ml = s & 31, ch = s >> 5;                                   \
            gl_lds16(th + (size_t)((M0) + ml) * 64 + ch * 8, &sb[BUF].hi[s * 8]); \
            gl_lds16(tl + (size_t)((M0) + ml) * 64 + ch * 8, &sb[BUF].lo[s * 8]); \
        }                                                                         \
        if (wu == 0 && lane < 8) gl_lds16(xb + (M0) + lane * 4, &sb[BUF].xm[0]);  \
    }

    KNN_STAGE(0, mbeg)

    for (int tt = 0; tt < 32; ++tt) {
        __syncthreads();
        if (tt < 31) KNN_STAGE((tt + 1) & 1, mbeg + (tt + 1) * 32)
        const KBuf& bf = sb[tt & 1];
        const int m0 = mbeg + tt * 32;

        float pds[2][4];   // [sub][r]
#pragma unroll
        for (int sub = 0; sub < 2; ++sub) {
            const int ml = sub * 16 + j;
            short8 bh0 = *(const short8*)&bf.hi[(q * 32 + ml) * 8];
            short8 bh1 = *(const short8*)&bf.hi[((4 + q) * 32 + ml) * 8];
            short8 bl0 = *(const short8*)&bf.lo[(q * 32 + ml) * 8];
            short8 bl1 = *(const short8*)&bf.lo[((4 + q) * 32 + ml) * 8];
            const float xmv = bf.xm[ml];
            f32x4 accA = (f32x4){0.f, 0.f, 0.f, 0.f};
            f32x4 accB = (f32x4){0.f, 0.f, 0.f, 0.f};
            accA = __builtin_amdgcn_mfma_f32_16x16x32_bf16(ah0, bh0, accA, 0, 0, 0);
            accB = __builtin_amdgcn_mfma_f32_16x16x32_bf16(ah1, bh1, accB, 0, 0, 0);
            accA = __builtin_amdgcn_mfma_f32_16x16x32_bf16(ah0, bl0, accA, 0, 0, 0);
            accB = __builtin_amdgcn_mfma_f32_16x16x32_bf16(ah1, bl1, accB, 0, 0, 0);
            accA = __builtin_amdgcn_mfma_f32_16x16x32_bf16(al0, bh0, accA, 0, 0, 0);
            accB = __builtin_amdgcn_mfma_f32_16x16x32_bf16(al1, bh1, accB, 0, 0, 0);
            accA = __builtin_amdgcn_mfma_f32_16x16x32_bf16(al0, bl0, accA, 0, 0, 0);
            accB = __builtin_amdgcn_mfma_f32_16x16x32_bf16(al1, bl1, accB, 0, 0, 0);
#pragma unroll
            for (int r = 0; r < 4; ++r)
                pds[sub][r] = __builtin_fmaf(2.f, accA[r] + accB[r], -xmv);
        }

#pragma unroll
        for (int r = 0; r < 4; ++r) {
            float mx = fmaxf(pds[0][r], pds[1][r]);
            if (fmap(mx) >= (unsigned int)(bk[r][3] >> 32)) {
#pragma unroll
                for (int sub = 0; sub < 2; ++sub) {
                    u64 key = mkkey(pds[sub][r], m0 + sub * 16 + j);
                    if (key > bk[r][3]) ins4k(key, bk[r]);
                }
            }
        }
    }
#undef KNN_STAGE

    // in-wave butterfly merge across the 16 j-lanes of each row
#pragma unroll
    for (int rr = 0; rr < 4; ++rr) {
#pragma unroll
        for (int mask = 1; mask < 16; mask <<= 1) {
            u64 pk[4];
#pragma unroll
            for (int s = 0; s < 4; ++s) pk[s] = __shfl_xor(bk[rr][s], mask, 64);
#pragma unroll
            for (int s = 0; s < 4; ++s) ins4k(pk[s], bk[rr]);
        }
    }
    if (j == 0) {
#pragma unroll
        for (int r = 0; r < 4; ++r) {
            const int nrow = nrow0 + q * 4 + r;
            u64* pp = part + (((size_t)b * 2 + mh) * 2048 + nrow) * 4;
            pp[0] = bk[r][0]; pp[1] = bk[r][1]; pp[2] = bk[r][2]; pp[3] = bk[r][3];
        }
    }
}

// =================================================================
// g-convs (gmax reduce inline) -> g3b (fp32) -> g4[b][o] = W4a[:,64:]@g3b
// =================================================================
__global__ __launch_bounds__(128) void gconv_kernel(
    const float* __restrict__ gp,
    const float* __restrict__ W3a, const float* __restrict__ s3a, const float* __restrict__ b3a,
    const float* __restrict__ W3b, const float* __restrict__ s3b, const float* __restrict__ b3b,
    const float* __restrict__ W4a, float* __restrict__ g4)
{
    const int b = blockIdx.x;
    const int t = threadIdx.x;
    __shared__ float gl[64], ga[128], gb[128];
    if (t < 64) {
        float m = -FLT_MAX;
        for (int s = 0; s < 64; ++s)
            m = fmaxf(m, gp[((size_t)b * 64 + s) * 64 + t]);
        gl[t] = m;
    }
    __syncthreads();
    float a = 0.f;
#pragma unroll
    for (int c = 0; c < 64; ++c) a += W3a[t * 64 + c] * gl[c];
    ga[t] = fmaxf(a * s3a[t] + b3a[t], 0.f);
    __syncthreads();
    float o = 0.f;
#pragma unroll
    for (int c = 0; c < 128; ++c) o += W3b[t * 128 + c] * ga[c];
    gb[t] = fmaxf(o * s3b[t] + b3b[t], 0.f);
    __syncthreads();
    for (int oo = t; oo < 256; oo += 128) {
        float s = 0.f;
#pragma unroll 4
        for (int c = 0; c < 128; ++c)
            s += W4a[(size_t)oo * 192 + 64 + c] * gb[c];
        g4[(size_t)b * 256 + oo] = s;
    }
}

// =================================================================
// Fused: knn-merge -> feat2a -> conv2b -> conv2c+maxk (LDS fin) ->
//        h4(K=64,+g4 bias) -> out projection.  Block = 4 waves = 16 n.
// Grid 1024 x 256 thr; ~24 KB LDS.
// =================================================================
__global__ __launch_bounds__(256) void fused_edge(
    const u64* __restrict__ part,
    const float* __restrict__ y, const float* __restrict__ z,
    const float* __restrict__ s2a, const float* __restrict__ b2a,
    const u16* __restrict__ w2bh, const u16* __restrict__ w2bl,
    const float* __restrict__ s2b, const float* __restrict__ b2b,
    const u16* __restrict__ w2ch, const u16* __restrict__ w2cl,
    const float* __restrict__ s2c, const float* __restrict__ b2c,
    const u16* __restrict__ w4ah, const u16* __restrict__ w4al,
    const float* __restrict__ b4a, const float* __restrict__ g4,
    const float* __restrict__ W4b, const float* __restrict__ b4b,
    float* __restrict__ out)
{
    const int t = threadIdx.x;
    const int wu = t >> 6;
    const int lane = t & 63;
    const int j = lane & 15, q = lane >> 4;
    const int b = blockIdx.x >> 7;
    const int n0 = (blockIdx.x & 127) * 16;
    const int nw0 = n0 + wu * 4;            // wave's 4 n

    __shared__ __align__(16) u16 plh[64 * 72];
    __shared__ __align__(16) u16 pll[64 * 72];
    __shared__ __align__(16) u16 finh[16 * 72];
    __shared__ __align__(16) u16 finl[16 * 72];
    __shared__ float pred[4][3][16];
    __shared__ int sidx[64];

    // ---- merge 2 half partial lists -> idx (lanes 0..3 per wave) ----
    if (lane < 4) {
        const int n = nw0 + lane;
        u64 fk[4] = {0ull, 0ull, 0ull, 0ull};
#pragma unroll
        for (int qt = 0; qt < 2; ++qt) {
            const u64* pp = part + (((size_t)b * 2 + qt) * 2048 + n) * 4;
#pragma unroll
            for (int s = 0; s < 4; ++s) ins4k(pp[s], fk);
        }
        int4 ii;
        ii.x = 2047 - (int)(fk[0] & 0x7ff);
        ii.y = 2047 - (int)(fk[1] & 0x7ff);
        ii.z = 2047 - (int)(fk[2] & 0x7ff);
        ii.w = 2047 - (int)(fk[3] & 0x7ff);
        *(int4*)&sidx[wu * 16 + lane * 4] = ii;
    }

    // ---- feat2a: lane handles 1 nk-row x 16 cols ----
    {
        const int row = lane >> 2;
        const int c0 = (lane & 3) * 16;
        const int id = sidx[wu * 16 + row];   // same-wave LDS dep (in-order DS)
        const int nfull = nw0 + (row >> 2);
        const float* yb = y + (size_t)b * 2048 * 64;
        const float* yi = yb + (size_t)id * 64;
        const float* yn = yb + (size_t)nfull * 64;
        const float* zn = z + ((size_t)b * 2048 + nfull) * 64;
        u16* oh = &plh[(wu * 16 + row) * 72 + c0];
        u16* ol = &pll[(wu * 16 + row) * 72 + c0];
#pragma unroll
        for (int cc = 0; cc < 16; cc += 4) {
            const int c = c0 + cc;
            float4 a  = *(const float4*)(yi + c);
            float4 bq = *(const float4*)(yn + c);
            float4 cq = *(const float4*)(zn + c);
            float4 sv = *(const float4*)(s2a + c);
            float4 bb = *(const float4*)(b2a + c);
            float v0 = fmaxf((a.x - bq.x + cq.x) * sv.x + bb.x, 0.f);
            float v1 = fmaxf((a.y - bq.y + cq.y) * sv.y + bb.y, 0.f);
            float v2 = fmaxf((a.z - bq.z + cq.z) * sv.z + bb.z, 0.f);
            float v3 = fmaxf((a.w - bq.w + cq.w) * sv.w + bb.w, 0.f);
            union { u16 u[4]; uint2 v; } ph, pl;
            split2(v0, ph.u[0], pl.u[0]);
            split2(v1, ph.u[1], pl.u[1]);
            split2(v2, ph.u[2], pl.u[2]);
            split2(v3, ph.u[3], pl.u[3]);
            *(uint2*)(oh + cc) = ph.v;
            *(uint2*)(ol + cc) = pl.v;
        }
    }

    // ---- conv2b (own 16 nk-rows), back to LDS ----
    {
        const int abase = (wu * 16 + j) * 72 + q * 8;
        short8 ah0 = *(const short8*)&plh[abase];
        short8 ah1 = *(const short8*)&plh[abase + 32];
        short8 al0 = *(const short8*)&pll[abase];
        short8 al1 = *(const short8*)&pll[abase + 32];
#pragma unroll
        for (int ct = 0; ct < 4; ++ct) {
            const int o = ct * 16 + j;
            short8 bh0 = *(const short8*)(w2bh + (size_t)o * 64 + q * 8);
            short8 bh1 = *(const short8*)(w2bh + (size_t)o * 64 + 32 + q * 8);
            short8 bl0 = *(const short8*)(w2bl + (size_t)o * 64 + q * 8);
            short8 bl1 = *(const short8*)(w2bl + (size_t)o * 64 + 32 + q * 8);
            f32x4 acc = (f32x4){0.f, 0.f, 0.f, 0.f};
            acc = __builtin_amdgcn_mfma_f32_16x16x32_bf16(ah0, bh0, acc, 0, 0, 0);
            acc = __builtin_amdgcn_mfma_f32_16x16x32_bf16(ah0, bl0, acc, 0, 0, 0);
            acc = __builtin_amdgcn_mfma_f32_16x16x32_bf16(al0, bh0, acc, 0, 0, 0);
            acc = __builtin_amdgcn_mfma_f32_16x16x32_bf16(ah1, bh1, acc, 0, 0, 0);
            acc = __builtin_amdgcn_mfma_f32_16x16x32_bf16(ah1, bl1, acc, 0, 0, 0);
            acc = __builtin_amdgcn_mfma_f32_16x16x32_bf16(al1, bh1, acc, 0, 0, 0);
            const float sc = s2b[o], bi = b2b[o];
#pragma unroll
            for (int r = 0; r < 4; ++r) {
                float v = fmaxf(acc[r] * sc + bi, 0.f);
                u16 h, l; split2(v, h, l);
                const int row = wu * 16 + q * 4 + r;
                plh[row * 72 + o] = h;
                pll[row * 72 + o] = l;
            }
        }
    }

    // ---- conv2c + max-over-k -> fin LDS tile (row = wu*4+q, col o) ----
    {
        const int abase = (wu * 16 + j) * 72 + q * 8;
        short8 ah0 = *(const short8*)&plh[abase];
        short8 ah1 = *(const short8*)&plh[abase + 32];
        short8 al0 = *(const short8*)&pll[abase];
        short8 al1 = *(const short8*)&pll[abase + 32];
#pragma unroll
        for (int ct = 0; ct < 4; ++ct) {
            const int o = ct * 16 + j;
            short8 bh0 = *(const short8*)(w2ch + (size_t)o * 64 + q * 8);
            short8 bh1 = *(const short8*)(w2ch + (size_t)o * 64 + 32 + q * 8);
            short8 bl0 = *(const short8*)(w2cl + (size_t)o * 64 + q * 8);
            short8 bl1 = *(const short8*)(w2cl + (size_t)o * 64 + 32 + q * 8);
            f32x4 acc = (f32x4){0.f, 0.f, 0.f, 0.f};
            acc = __builtin_amdgcn_mfma_f32_16x16x32_bf16(ah0, bh0, acc, 0, 0, 0);
            acc = __builtin_amdgcn_mfma_f32_16x16x32_bf16(ah0, bl0, acc, 0, 0, 0);
            acc = __builtin_amdgcn_mfma_f32_16x16x32_bf16(al0, bh0, acc, 0, 0, 0);
            acc = __builtin_amdgcn_mfma_f32_16x16x32_bf16(ah1, bh1, acc, 0, 0, 0);
            acc = __builtin_amdgcn_mfma_f32_16x16x32_bf16(ah1, bl1, acc, 0, 0, 0);
            acc = __builtin_amdgcn_mfma_f32_16x16x32_bf16(al1, bh1, acc, 0, 0, 0);
            const float sc = s2c[o], bi = b2c[o];
            float m = -FLT_MAX;
#pragma unroll
            for (int r = 0; r < 4; ++r)
                m = fmaxf(m, fmaxf(acc[r] * sc + bi, 0.f));
            u16 h, l; split2(m, h, l);
            const int frow = wu * 4 + q;
            finh[frow * 72 + o] = h;
            finl[frow * 72 + o] = l;
        }
    }
    __syncthreads();

    // ---- h4 (K=64) on the 16-row fin tile; wave covers cts wu*4..wu*4+3 ----
    {
        short8 a_hi[2], a_lo[2];
#pragma unroll
        for (int ks = 0; ks < 2; ++ks) {
            a_hi[ks] = *(const short8*)&finh[j * 72 + q * 8 + ks * 32];
            a_lo[ks] = *(const short8*)&finl[j * 72 + q * 8 + ks * 32];
        }
        float p[3][4];
#pragma unroll
        for (int oo = 0; oo < 3; ++oo)
#pragma unroll
            for (int r = 0; r < 4; ++r) p[oo][r] = 0.f;

#pragma unroll
        for (int ci = 0; ci < 4; ++ci) {
            const int o = (wu * 4 + ci) * 16 + j;
            const u16* wr_h = w4ah + (size_t)o * 192 + q * 8;
            const u16* wr_l = w4al + (size_t)o * 192 + q * 8;
            f32x4 acc = (f32x4){0.f, 0.f, 0.f, 0.f};
#pragma unroll
            for (int ks = 0; ks < 2; ++ks) {
                short8 bh = *(const short8*)(wr_h + ks * 32);
                short8 bl = *(const short8*)(wr_l + ks * 32);
                acc = __builtin_amdgcn_mfma_f32_16x16x32_bf16(a_hi[ks], bh, acc, 0, 0, 0);
                acc = __builtin_amdgcn_mfma_f32_16x16x32_bf16(a_hi[ks], bl, acc, 0, 0, 0);
                acc = __builtin_amdgcn_mfma_f32_16x16x32_bf16(a_lo[ks], bh, acc, 0, 0, 0);
            }
            const float bi = b4a[o] + g4[(size_t)b * 256 + o];
            float w0 = W4b[o], w1 = W4b[256 + o], w2 = W4b[512 + o];
#pragma unroll
            for (int r = 0; r < 4; ++r) {
                float v = fmaxf(acc[r] + bi, 0.f);
                p[0][r] += w0 * v;
                p[1][r] += w1 * v;
                p[2][r] += w2 * v;
            }
        }
#pragma unroll
        for (int oo = 0; oo < 3; ++oo)
#pragma unroll
            for (int r = 0; r < 4; ++r) {
#pragma unroll
                for (int mask = 1; mask < 16; mask <<= 1)
                    p[oo][r] += __shfl_xor(p[oo][r], mask, 64);
            }
        if (j == 0) {
#pragma unroll
            for (int oo = 0; oo < 3; ++oo)
#pragma unroll
                for (int r = 0; r < 4; ++r)
                    pred[wu][oo][q * 4 + r] = p[oo][r];
        }
    }
    __syncthreads();

    if (t < 48) {
        const int oo = t >> 4, rr = t & 15;
        float s = (pred[0][oo][rr] + pred[1][oo][rr]) +
                  (pred[2][oo][rr] + pred[3][oo][rr]) + b4b[oo];
        out[((size_t)b * 3 + oo) * 2048 + n0 + rr] = s;
    }
}

extern "C" void kernel_launch(void* const* d_in, const int* in_sizes, int n_in,
                              void* d_out, int out_size, void* d_ws, size_t ws_size,
                              hipStream_t stream)
{
    const float* x     = (const float*)d_in[0];
    const float* W_dup = (const float*)d_in[1];
    const float* s_dup = (const float*)d_in[2];
    const float* b_dup = (const float*)d_in[3];
    const float* W_c1  = (const float*)d_in[4];
    const float* s_c1  = (const float*)d_in[5];
    const float* b_c1  = (const float*)d_in[6];
    const float* W2a   = (const float*)d_in[7];
    const float* s2a   = (const float*)d_in[8];
    const float* b2a   = (const float*)d_in[9];
    const float* W2b   = (const float*)d_in[10];
    const float* s2b   = (const float*)d_in[11];
    const float* b2b   = (const float*)d_in[12];
    const float* W2c   = (const float*)d_in[13];
    const float* s2c   = (const float*)d_in[14];
    const float* b2c   = (const float*)d_in[15];
    const float* W3a   = (const float*)d_in[16];
    const float* s3a   = (const float*)d_in[17];
    const float* b3a   = (const float*)d_in[18];
    const float* W3b   = (const float*)d_in[19];
    const float* s3b   = (const float*)d_in[20];
    const float* b3b   = (const float*)d_in[21];
    const float* W4a   = (const float*)d_in[22];
    const float* b4a   = (const float*)d_in[23];
    const float* W4b   = (const float*)d_in[24];
    const float* b4b   = (const float*)d_in[25];

    if (ws_size < WS_FLOATS * sizeof(float)) return;

    float* ws = (float*)d_ws;
    u16* whi   = (u16*)(ws + OFF_W);
    u16* wlo   = whi + 131072;
    u16* xthi  = (u16*)(ws + OFF_FEATR);
    u16* xtlo  = xthi + 1048576;
    u64* part  = (u64*)(ws + OFF_FEATR);   // xt dead by knn time
    float* y    = ws + OFF_YZ;
    float* z    = ws + OFF_Zf;
    u16* h2thi = (u16*)(ws + OFF_FIN);
    u16* h2tlo = h2thi + 1048576;
    float* xxb  = ws + OFF_XX;
    float* gp   = ws + OFF_G;
    float* g4   = ws + OFF_G4;
    float* out  = (float*)d_out;

    // 0) prep: weight split + x transpose-split
    prep<<<672, 256, 0, stream>>>(W_dup, W_c1, W2a, W2b, W2c, W4a, x,
                                  whi, wlo, xthi, xtlo);
    // 1) backbone: conv1 -> h2(+xx,+gmax) -> y,z
    backbone<<<dim3(64, 8), 512, 0, stream>>>(
        xthi, xtlo, whi, wlo, s_dup, b_dup, s_c1, b_c1,
        h2thi, h2tlo, xxb, gp, y, z);
    // 2) g-convs + g4 projection
    gconv_kernel<<<8, 128, 0, stream>>>(gp, W3a, s3a, b3a, W3b, s3b, b3b, W4a, g4);
    // 3) kNN (m-halves, 2-wave blocks, 32-m tiles)
    knn_topk<<<dim3(64, 2, 8), 128, 0, stream>>>(h2thi, h2tlo, xxb, part);
    // 4) fused merge+feat2a+conv2b+conv2c+maxk+h4+projection -> out
    fused_edge<<<1024, 256, 0, stream>>>(
        part, y, z, s2a, b2a,
        whi + WO_2B, wlo + WO_2B, s2b, b2b,
        whi + WO_2C, wlo + WO_2C, s2c, b2c,
        whi + WO_4A, wlo + WO_4A, b4a, g4, W4b, b4b, out);
}

// Round 12
// 219.309 us; speedup vs baseline: 1.1231x; 1.1231x over previous
//
#include <hip/hip_runtime.h>
#include <float.h>

typedef __attribute__((ext_vector_type(8))) short short8;   // 8 bf16 (4 VGPRs)
typedef __attribute__((ext_vector_type(4))) float f32x4;    // MFMA C/D
typedef unsigned short u16;
typedef unsigned long long u64;

// ---------------- workspace layout (float offsets), lifetime-aliased ----------------
static constexpr size_t OFF_W     = 0;          // weight hi/lo planes (persistent)
static constexpr size_t OFF_YZ    = 131072;     // y fp32 [8*2048][64]
static constexpr size_t OFF_Zf    = 1179648;    // z fp32
static constexpr size_t OFF_FEATR = 2228224;    // knn part (u64)
static constexpr size_t OFF_FIN   = 6422528;    // h2t hi/lo
static constexpr size_t OFF_XX    = 9568256;    // 16384
static constexpr size_t OFF_G     = 9584640;    // gmax partials 8*64*64 = 32768
static constexpr size_t OFF_G4    = 9617408;    // g4 fp32 8*256 = 2048
static constexpr size_t WS_FLOATS = 9652736;    // ~38.6 MB

// weight sub-offsets (u16 elements within each plane)
static constexpr size_t WO_DUP = 0;       // 256x128
static constexpr size_t WO_C1  = 32768;   // 64x128
static constexpr size_t WO_2A  = 40960;   // 64x128
static constexpr size_t WO_2B  = 49152;   // 64x64
static constexpr size_t WO_2C  = 53248;   // 64x64
static constexpr size_t WO_4A  = 57344;   // 256x192

// async 16B global->LDS (wave-uniform base + lane*16)
__device__ __forceinline__ void gl_lds16(const void* g, void* l) {
    __builtin_amdgcn_global_load_lds(
        (const __attribute__((address_space(1))) void*)g,
        (__attribute__((address_space(3))) void*)l, 16, 0, 0);
}

__device__ __forceinline__ u16 f2bf(float x) {
    union { float f; unsigned int u; } v; v.f = x;
    unsigned int r = v.u + 0x7fffu + ((v.u >> 16) & 1u);
    return (u16)(r >> 16);
}
__device__ __forceinline__ float bf2f(u16 h) {
    union { unsigned int u; float f; } v; v.u = ((unsigned int)h) << 16;
    return v.f;
}
__device__ __forceinline__ void split2(float x, u16& h, u16& l) {
    h = f2bf(x);
    l = f2bf(x - bf2f(h));
}

// monotone float->uint map (exact, no NaNs here)
__device__ __forceinline__ unsigned int fmap(float f) {
    unsigned int u = __float_as_uint(f);
    return u ^ ((unsigned int)((int)u >> 31) | 0x80000000u);
}
// key: high32 = mapped value, low32 = 2047-m  (desc value, asc index)
__device__ __forceinline__ u64 mkkey(float f, int m) {
    return ((u64)fmap(f) << 32) | (unsigned int)(2047 - m);
}
// sorted-desc top-4 insert on u64 keys
static __device__ __forceinline__ void ins4k(u64 k, u64 bk[4])
{
#pragma unroll
    for (int s = 0; s < 4; ++s) {
        bool better = k > bk[s];
        u64 t = bk[s];
        bk[s] = better ? k : bk[s];
        k = better ? t : k;
    }
}

// =================================================================
// PREP: weight split only (x-transpose moved into backbone)
// =================================================================
__global__ __launch_bounds__(256) void prep(
    const float* __restrict__ W_dup, const float* __restrict__ W_c1,
    const float* __restrict__ W2a, const float* __restrict__ W2b,
    const float* __restrict__ W2c, const float* __restrict__ W4a,
    u16* __restrict__ whi, u16* __restrict__ wlo)
{
    int t = blockIdx.x * 256 + threadIdx.x;   // 106,496 -> 416 blocks
    float v;
    if      (t < 40960) v = (t < 32768) ? W_dup[t] : W_c1[t - 32768];
    else if (t < 53248) v = (t < 49152) ? W2a[t - 40960] : W2b[t - 49152];
    else                v = (t < 57344) ? W2c[t - 53248] : W4a[t - 57344];
    u16 h, l; split2(v, h, l);
    whi[t] = h; wlo[t] = l;
}

// =================================================================
// BACKBONE: x-tile LDS split -> conv1(+reshape) -> h2(+xx,+gmax) -> y,z
// 512 threads = 8 waves; grid (64 nblocks, 8 b) = 512.
// =================================================================
__global__ __launch_bounds__(512) void backbone(
    const float* __restrict__ x,
    const u16* __restrict__ whi, const u16* __restrict__ wlo,
    const float* __restrict__ s_dup, const float* __restrict__ b_dup,
    const float* __restrict__ s_c1, const float* __restrict__ b_c1,
    u16* __restrict__ h2thi, u16* __restrict__ h2tlo,
    float* __restrict__ xxb, float* __restrict__ gp,
    float* __restrict__ y, float* __restrict__ z)
{
    const int t = threadIdx.x;
    const int wu = t >> 6;              // 0..7
    const int lane = t & 63;
    const int j = lane & 15, q = lane >> 4;
    const int nb = blockIdx.x;          // 0..63
    const int b  = blockIdx.y;          // 0..7
    const int n0 = nb * 16;

    __shared__ __align__(16) u16 xh[16 * 136], xl[16 * 136];     // x tile [n][c]
    __shared__ __align__(16) u16 h1h[32 * 136], h1l[32 * 136];
    __shared__ __align__(16) u16 h2h[32 * 72],  h2l[32 * 72];
    __shared__ float xxp[2][4][16];
    __shared__ float gpart[2][64];

    // ---- stage 0: load x[b][c][n0..n0+16) -> split LDS planes [n][c] ----
    {
        const int c = t >> 2, i4 = (t & 3) * 4;
        float4 xv = *(const float4*)(x + ((size_t)b * 128 + c) * 1024 + n0 + i4);
        u16 h, l;
        split2(xv.x, h, l); xh[(i4 + 0) * 136 + c] = h; xl[(i4 + 0) * 136 + c] = l;
        split2(xv.y, h, l); xh[(i4 + 1) * 136 + c] = h; xl[(i4 + 1) * 136 + c] = l;
        split2(xv.z, h, l); xh[(i4 + 2) * 136 + c] = h; xl[(i4 + 2) * 136 + c] = l;
        split2(xv.w, h, l); xh[(i4 + 3) * 136 + c] = h; xl[(i4 + 3) * 136 + c] = l;
    }
    __syncthreads();

    // ---- stage A: conv1 (K=128), 16 n-rows, 256 outs; wave: 2 col-tiles ----
    {
        short8 ahv[4], alv[4];
#pragma unroll
        for (int ks = 0; ks < 4; ++ks) {
            ahv[ks] = *(const short8*)&xh[j * 136 + q * 8 + ks * 32];
            alv[ks] = *(const short8*)&xl[j * 136 + q * 8 + ks * 32];
        }
        const u16* wdh = whi + WO_DUP;
        const u16* wdl = wlo + WO_DUP;
#pragma unroll
        for (int ci = 0; ci < 2; ++ci) {
            const int ctile = wu * 2 + ci;
            const int o = ctile * 16 + j;
            f32x4 acc = (f32x4){0.f, 0.f, 0.f, 0.f};
#pragma unroll
            for (int ks = 0; ks < 4; ++ks) {
                short8 bh = *(const short8*)(wdh + (size_t)o * 128 + q * 8 + ks * 32);
                short8 bl = *(const short8*)(wdl + (size_t)o * 128 + q * 8 + ks * 32);
                acc = __builtin_amdgcn_mfma_f32_16x16x32_bf16(ahv[ks], bh, acc, 0, 0, 0);
                acc = __builtin_amdgcn_mfma_f32_16x16x32_bf16(ahv[ks], bl, acc, 0, 0, 0);
                acc = __builtin_amdgcn_mfma_f32_16x16x32_bf16(alv[ks], bh, acc, 0, 0, 0);
            }
            const float sc = s_dup[o], bi = b_dup[o];
            const int lrbase = (j & 1) * 16;
            const int col = ctile * 8 + (j >> 1);
#pragma unroll
            for (int r = 0; r < 4; ++r) {
                float v = fmaxf(acc[r] * sc + bi, 0.f);
                u16 h, l; split2(v, h, l);
                const int lr = lrbase + q * 4 + r;
                h1h[lr * 136 + col] = h;
                h1l[lr * 136 + col] = l;
            }
        }
    }
    __syncthreads();

    // ---- stage B: h2 (K=128) on 32 h1r rows; wave = (row-group g, col-quad cq) ----
    {
        const int g = wu >> 2, cq = wu & 3;
        short8 ahv[4], alv[4];
#pragma unroll
        for (int ks = 0; ks < 4; ++ks) {
            ahv[ks] = *(const short8*)&h1h[(g * 16 + j) * 136 + q * 8 + ks * 32];
            alv[ks] = *(const short8*)&h1l[(g * 16 + j) * 136 + q * 8 + ks * 32];
        }
        const u16* wch = whi + WO_C1;
        const u16* wcl = wlo + WO_C1;
        const int o = cq * 16 + j;
        f32x4 acc = (f32x4){0.f, 0.f, 0.f, 0.f};
#pragma unroll
        for (int ks = 0; ks < 4; ++ks) {
            short8 bh = *(const short8*)(wch + (size_t)o * 128 + q * 8 + ks * 32);
            short8 bl = *(const short8*)(wcl + (size_t)o * 128 + q * 8 + ks * 32);
            acc = __builtin_amdgcn_mfma_f32_16x16x32_bf16(ahv[ks], bh, acc, 0, 0, 0);
            acc = __builtin_amdgcn_mfma_f32_16x16x32_bf16(ahv[ks], bl, acc, 0, 0, 0);
            acc = __builtin_amdgcn_mfma_f32_16x16x32_bf16(alv[ks], bh, acc, 0, 0, 0);
        }
        const float sc = s_c1[o], bi = b_c1[o];
        float sq[4];
        float cm = -FLT_MAX;
#pragma unroll
        for (int r = 0; r < 4; ++r) {
            float v = fmaxf(acc[r] * sc + bi, 0.f);
            sq[r] = v * v;
            cm = fmaxf(cm, v);
            u16 h, l; split2(v, h, l);
            const size_t R = (size_t)b * 2048 + g * 1024 + n0 + q * 4 + r;
            h2thi[R * 64 + o] = h;
            h2tlo[R * 64 + o] = l;
            const int lr = g * 16 + q * 4 + r;
            h2h[lr * 72 + o] = h;
            h2l[lr * 72 + o] = l;
        }
#pragma unroll
        for (int r = 0; r < 4; ++r) {
#pragma unroll
            for (int mask = 1; mask < 16; mask <<= 1)
                sq[r] += __shfl_xor(sq[r], mask, 64);
        }
        if (j == 0) {
#pragma unroll
            for (int r = 0; r < 4; ++r) xxp[g][cq][q * 4 + r] = sq[r];
        }
        cm = fmaxf(cm, __shfl_xor(cm, 16, 64));
        cm = fmaxf(cm, __shfl_xor(cm, 32, 64));
        if (q == 0) gpart[g][cq * 16 + j] = cm;
    }
    __syncthreads();

    if (t < 32) {
        const int g = t >> 4, i = t & 15;
        xxb[(size_t)b * 2048 + g * 1024 + n0 + i] =
            (xxp[g][0][i] + xxp[g][1][i]) + (xxp[g][2][i] + xxp[g][3][i]);
    }
    if (t >= 64 && t < 128) {
        const int c = t - 64;
        gp[((size_t)b * 64 + nb) * 64 + c] = fmaxf(gpart[0][c], gpart[1][c]);
    }

    // ---- stage C: y,z (K=64) from LDS h2 tile ----
    {
        const int g = wu >> 2, half = (wu >> 1) & 1, cg = wu & 1;
        short8 ahv[2], alv[2];
#pragma unroll
        for (int ks = 0; ks < 2; ++ks) {
            ahv[ks] = *(const short8*)&h2h[(g * 16 + j) * 72 + q * 8 + ks * 32];
            alv[ks] = *(const short8*)&h2l[(g * 16 + j) * 72 + q * 8 + ks * 32];
        }
        const u16* w2h = whi + WO_2A;
        const u16* w2l = wlo + WO_2A;
        float* dst = half ? z : y;
#pragma unroll
        for (int ci = 0; ci < 2; ++ci) {
            const int o = (cg * 2 + ci) * 16 + j;
            f32x4 acc = (f32x4){0.f, 0.f, 0.f, 0.f};
#pragma unroll
            for (int ks = 0; ks < 2; ++ks) {
                short8 bh = *(const short8*)(w2h + (size_t)o * 128 + half * 64 + q * 8 + ks * 32);
                short8 bl = *(const short8*)(w2l + (size_t)o * 128 + half * 64 + q * 8 + ks * 32);
                acc = __builtin_amdgcn_mfma_f32_16x16x32_bf16(ahv[ks], bh, acc, 0, 0, 0);
                acc = __builtin_amdgcn_mfma_f32_16x16x32_bf16(ahv[ks], bl, acc, 0, 0, 0);
                acc = __builtin_amdgcn_mfma_f32_16x16x32_bf16(alv[ks], bh, acc, 0, 0, 0);
            }
#pragma unroll
            for (int r = 0; r < 4; ++r) {
                const size_t R = (size_t)b * 2048 + g * 1024 + n0 + q * 4 + r;
                dst[R * 64 + o] = acc[r];
            }
        }
    }
}

// =================================================================
// kNN (exact r9 config: 4-wave, 64-m tiles, m-halves, u64 keys) with
// gconv folded in: grid (32, 2, 9); z==8 strip runs gconv.
// =================================================================
struct __align__(16) KBuf {
    u16 hi[4096];
    u16 lo[4096];
    float xm[64];
};

__global__ __launch_bounds__(256) void knn_gconv(
    const u16* __restrict__ thi, const u16* __restrict__ tlo,
    const float* __restrict__ xx, u64* __restrict__ part,
    const float* __restrict__ gp,
    const float* __restrict__ W3a, const float* __restrict__ s3a, const float* __restrict__ b3a,
    const float* __restrict__ W3b, const float* __restrict__ s3b, const float* __restrict__ b3b,
    const float* __restrict__ W4a, float* __restrict__ g4)
{
    __shared__ KBuf sb[2];
    __shared__ float gl[64], ga[128], gbv[128];

    if (blockIdx.z == 8) {
        // ---------- gconv strip ----------
        if (blockIdx.y != 0 || blockIdx.x >= 8) return;
        const int b = blockIdx.x;
        const int t = threadIdx.x;
        if (t < 64) {
            float m = -FLT_MAX;
            for (int s = 0; s < 64; ++s)
                m = fmaxf(m, gp[((size_t)b * 64 + s) * 64 + t]);
            gl[t] = m;
        }
        __syncthreads();
        if (t < 128) {
            float a = 0.f;
#pragma unroll
            for (int c = 0; c < 64; ++c) a += W3a[t * 64 + c] * gl[c];
            ga[t] = fmaxf(a * s3a[t] + b3a[t], 0.f);
        }
        __syncthreads();
        if (t < 128) {
            float o = 0.f;
#pragma unroll
            for (int c = 0; c < 128; ++c) o += W3b[t * 128 + c] * ga[c];
            gbv[t] = fmaxf(o * s3b[t] + b3b[t], 0.f);
        }
        __syncthreads();
        if (t < 128) {
            for (int oo = t; oo < 256; oo += 128) {
                float s = 0.f;
#pragma unroll 4
                for (int c = 0; c < 128; ++c)
                    s += W4a[(size_t)oo * 192 + 64 + c] * gbv[c];
                g4[(size_t)b * 256 + oo] = s;
            }
        }
        return;
    }

    // ---------- kNN ----------
    const int b    = blockIdx.z;
    const int mh   = blockIdx.y;
    const int t    = threadIdx.x;
    const int wu   = __builtin_amdgcn_readfirstlane(t >> 6);
    const int lane = t & 63;
    const int j    = lane & 15;
    const int q    = lane >> 4;
    const int nrow0 = blockIdx.x * 64 + wu * 16;

    const u16* th = thi + (size_t)b * 2048 * 64;
    const u16* tl = tlo + (size_t)b * 2048 * 64;
    const float* xb = xx + (size_t)b * 2048;

    const size_t arow = (size_t)(nrow0 + j) * 64;
    short8 ah0 = *(const short8*)(th + arow + q * 8);
    short8 ah1 = *(const short8*)(th + arow + 32 + q * 8);
    short8 al0 = *(const short8*)(tl + arow + q * 8);
    short8 al1 = *(const short8*)(tl + arow + 32 + q * 8);

    u64 bk[4][4];
#pragma unroll
    for (int r = 0; r < 4; ++r)
#pragma unroll
        for (int s = 0; s < 4; ++s) bk[r][s] = 0ull;

    const int mbeg = mh * 1024;

#define KNN_STAGE(BUF, M0)                                                        \
    {                                                                             \
        const u16* sh = th + (size_t)((M0) + lane) * 64;                          \
        const u16* sl = tl + (size_t)((M0) + lane) * 64;                          \
        gl_lds16(sh + (2 * wu) * 8,     &sb[BUF].hi[(2 * wu) * 512]);             \
        gl_lds16(sh + (2 * wu + 1) * 8, &sb[BUF].hi[(2 * wu + 1) * 512]);         \
        gl_lds16(sl + (2 * wu) * 8,     &sb[BUF].lo[(2 * wu) * 512]);             \
        gl_lds16(sl + (2 * wu + 1) * 8, &sb[BUF].lo[(2 * wu + 1) * 512]);         \
        if (wu == 0 && lane < 16) gl_lds16(xb + (M0) + lane * 4, &sb[BUF].xm[0]); \
    }

    KNN_STAGE(0, mbeg)

    for (int tt = 0; tt < 16; ++tt) {
        __syncthreads();
        if (tt < 15) KNN_STAGE((tt + 1) & 1, mbeg + (tt + 1) * 64)
        const KBuf& bf = sb[tt & 1];
        const int m0 = mbeg + tt * 64;

        float pds[4][4];   // [sub][r]
#pragma unroll
        for (int sub = 0; sub < 4; ++sub) {
            const int ml = sub * 16 + j;
            short8 bh0 = *(const short8*)&bf.hi[(q) * 512 + ml * 8];
            short8 bh1 = *(const short8*)&bf.hi[(4 + q) * 512 + ml * 8];
            short8 bl0 = *(const short8*)&bf.lo[(q) * 512 + ml * 8];
            short8 bl1 = *(const short8*)&bf.lo[(4 + q) * 512 + ml * 8];
            const float xmv = bf.xm[ml];
            f32x4 accA = (f32x4){0.f, 0.f, 0.f, 0.f};
            f32x4 accB = (f32x4){0.f, 0.f, 0.f, 0.f};
            accA = __builtin_amdgcn_mfma_f32_16x16x32_bf16(ah0, bh0, accA, 0, 0, 0);
            accB = __builtin_amdgcn_mfma_f32_16x16x32_bf16(ah1, bh1, accB, 0, 0, 0);
            accA = __builtin_amdgcn_mfma_f32_16x16x32_bf16(ah0, bl0, accA, 0, 0, 0);
            accB = __builtin_amdgcn_mfma_f32_16x16x32_bf16(ah1, bl1, accB, 0, 0, 0);
            accA = __builtin_amdgcn_mfma_f32_16x16x32_bf16(al0, bh0, accA, 0, 0, 0);
            accB = __builtin_amdgcn_mfma_f32_16x16x32_bf16(al1, bh1, accB, 0, 0, 0);
            accA = __builtin_amdgcn_mfma_f32_16x16x32_bf16(al0, bl0, accA, 0, 0, 0);
            accB = __builtin_amdgcn_mfma_f32_16x16x32_bf16(al1, bl1, accB, 0, 0, 0);
#pragma unroll
            for (int r = 0; r < 4; ++r)
                pds[sub][r] = __builtin_fmaf(2.f, accA[r] + accB[r], -xmv);
        }

#pragma unroll
        for (int r = 0; r < 4; ++r) {
            float mx = fmaxf(fmaxf(pds[0][r], pds[1][r]), fmaxf(pds[2][r], pds[3][r]));
            if (fmap(mx) >= (unsigned int)(bk[r][3] >> 32)) {
#pragma unroll
                for (int sub = 0; sub < 4; ++sub) {
                    u64 key = mkkey(pds[sub][r], m0 + sub * 16 + j);
                    if (key > bk[r][3]) ins4k(key, bk[r]);
                }
            }
        }
    }
#undef KNN_STAGE

    // in-wave butterfly merge across the 16 j-lanes of each row
#pragma unroll
    for (int rr = 0; rr < 4; ++rr) {
#pragma unroll
        for (int mask = 1; mask < 16; mask <<= 1) {
            u64 pk[4];
#pragma unroll
            for (int s = 0; s < 4; ++s) pk[s] = __shfl_xor(bk[rr][s], mask, 64);
#pragma unroll
            for (int s = 0; s < 4; ++s) ins4k(pk[s], bk[rr]);
        }
    }
    if (j == 0) {
#pragma unroll
        for (int r = 0; r < 4; ++r) {
            const int nrow = nrow0 + q * 4 + r;
            u64* pp = part + (((size_t)b * 2 + mh) * 2048 + nrow) * 4;
            pp[0] = bk[r][0]; pp[1] = bk[r][1]; pp[2] = bk[r][2]; pp[3] = bk[r][3];
        }
    }
}

// =================================================================
// Fused: knn-merge -> feat2a -> conv2b -> conv2c+maxk (LDS fin) ->
//        h4(K=64,+g4 bias) -> out projection. (unchanged r11)
// =================================================================
__global__ __launch_bounds__(256) void fused_edge(
    const u64* __restrict__ part,
    const float* __restrict__ y, const float* __restrict__ z,
    const float* __restrict__ s2a, const float* __restrict__ b2a,
    const u16* __restrict__ w2bh, const u16* __restrict__ w2bl,
    const float* __restrict__ s2b, const float* __restrict__ b2b,
    const u16* __restrict__ w2ch, const u16* __restrict__ w2cl,
    const float* __restrict__ s2c, const float* __restrict__ b2c,
    const u16* __restrict__ w4ah, const u16* __restrict__ w4al,
    const float* __restrict__ b4a, const float* __restrict__ g4,
    const float* __restrict__ W4b, const float* __restrict__ b4b,
    float* __restrict__ out)
{
    const int t = threadIdx.x;
    const int wu = t >> 6;
    const int lane = t & 63;
    const int j = lane & 15, q = lane >> 4;
    const int b = blockIdx.x >> 7;
    const int n0 = (blockIdx.x & 127) * 16;
    const int nw0 = n0 + wu * 4;

    __shared__ __align__(16) u16 plh[64 * 72];
    __shared__ __align__(16) u16 pll[64 * 72];
    __shared__ __align__(16) u16 finh[16 * 72];
    __shared__ __align__(16) u16 finl[16 * 72];
    __shared__ float pred[4][3][16];
    __shared__ int sidx[64];

    if (lane < 4) {
        const int n = nw0 + lane;
        u64 fk[4] = {0ull, 0ull, 0ull, 0ull};
#pragma unroll
        for (int qt = 0; qt < 2; ++qt) {
            const u64* pp = part + (((size_t)b * 2 + qt) * 2048 + n) * 4;
#pragma unroll
            for (int s = 0; s < 4; ++s) ins4k(pp[s], fk);
        }
        int4 ii;
        ii.x = 2047 - (int)(fk[0] & 0x7ff);
        ii.y = 2047 - (int)(fk[1] & 0x7ff);
        ii.z = 2047 - (int)(fk[2] & 0x7ff);
        ii.w = 2047 - (int)(fk[3] & 0x7ff);
        *(int4*)&sidx[wu * 16 + lane * 4] = ii;
    }

    {
        const int row = lane >> 2;
        const int c0 = (lane & 3) * 16;
        const int id = sidx[wu * 16 + row];
        const int nfull = nw0 + (row >> 2);
        const float* yb = y + (size_t)b * 2048 * 64;
        const float* yi = yb + (size_t)id * 64;
        const float* yn = yb + (size_t)nfull * 64;
        const float* zn = z + ((size_t)b * 2048 + nfull) * 64;
        u16* oh = &plh[(wu * 16 + row) * 72 + c0];
        u16* ol = &pll[(wu * 16 + row) * 72 + c0];
#pragma unroll
        for (int cc = 0; cc < 16; cc += 4) {
            const int c = c0 + cc;
            float4 a  = *(const float4*)(yi + c);
            float4 bq = *(const float4*)(yn + c);
            float4 cq = *(const float4*)(zn + c);
            float4 sv = *(const float4*)(s2a + c);
            float4 bb = *(const float4*)(b2a + c);
            float v0 = fmaxf((a.x - bq.x + cq.x) * sv.x + bb.x, 0.f);
            float v1 = fmaxf((a.y - bq.y + cq.y) * sv.y + bb.y, 0.f);
            float v2 = fmaxf((a.z - bq.z + cq.z) * sv.z + bb.z, 0.f);
            float v3 = fmaxf((a.w - bq.w + cq.w) * sv.w + bb.w, 0.f);
            union { u16 u[4]; uint2 v; } ph, pl;
            split2(v0, ph.u[0], pl.u[0]);
            split2(v1, ph.u[1], pl.u[1]);
            split2(v2, ph.u[2], pl.u[2]);
            split2(v3, ph.u[3], pl.u[3]);
            *(uint2*)(oh + cc) = ph.v;
            *(uint2*)(ol + cc) = pl.v;
        }
    }

    {
        const int abase = (wu * 16 + j) * 72 + q * 8;
        short8 ah0 = *(const short8*)&plh[abase];
        short8 ah1 = *(const short8*)&plh[abase + 32];
        short8 al0 = *(const short8*)&pll[abase];
        short8 al1 = *(const short8*)&pll[abase + 32];
#pragma unroll
        for (int ct = 0; ct < 4; ++ct) {
            const int o = ct * 16 + j;
            short8 bh0 = *(const short8*)(w2bh + (size_t)o * 64 + q * 8);
            short8 bh1 = *(const short8*)(w2bh + (size_t)o * 64 + 32 + q * 8);
            short8 bl0 = *(const short8*)(w2bl + (size_t)o * 64 + q * 8);
            short8 bl1 = *(const short8*)(w2bl + (size_t)o * 64 + 32 + q * 8);
            f32x4 acc = (f32x4){0.f, 0.f, 0.f, 0.f};
            acc = __builtin_amdgcn_mfma_f32_16x16x32_bf16(ah0, bh0, acc, 0, 0, 0);
            acc = __builtin_amdgcn_mfma_f32_16x16x32_bf16(ah0, bl0, acc, 0, 0, 0);
            acc = __builtin_amdgcn_mfma_f32_16x16x32_bf16(al0, bh0, acc, 0, 0, 0);
            acc = __builtin_amdgcn_mfma_f32_16x16x32_bf16(ah1, bh1, acc, 0, 0, 0);
            acc = __builtin_amdgcn_mfma_f32_16x16x32_bf16(ah1, bl1, acc, 0, 0, 0);
            acc = __builtin_amdgcn_mfma_f32_16x16x32_bf16(al1, bh1, acc, 0, 0, 0);
            const float sc = s2b[o], bi = b2b[o];
#pragma unroll
            for (int r = 0; r < 4; ++r) {
                float v = fmaxf(acc[r] * sc + bi, 0.f);
                u16 h, l; split2(v, h, l);
                const int row = wu * 16 + q * 4 + r;
                plh[row * 72 + o] = h;
                pll[row * 72 + o] = l;
            }
        }
    }

    {
        const int abase = (wu * 16 + j) * 72 + q * 8;
        short8 ah0 = *(const short8*)&plh[abase];
        short8 ah1 = *(const short8*)&plh[abase + 32];
        short8 al0 = *(const short8*)&pll[abase];
        short8 al1 = *(const short8*)&pll[abase + 32];
#pragma unroll
        for (int ct = 0; ct < 4; ++ct) {
            const int o = ct * 16 + j;
            short8 bh0 = *(const short8*)(w2ch + (size_t)o * 64 + q * 8);
            short8 bh1 = *(const short8*)(w2ch + (size_t)o * 64 + 32 + q * 8);
            short8 bl0 = *(const short8*)(w2cl + (size_t)o * 64 + q * 8);
            short8 bl1 = *(const short8*)(w2cl + (size_t)o * 64 + 32 + q * 8);
            f32x4 acc = (f32x4){0.f, 0.f, 0.f, 0.f};
            acc = __builtin_amdgcn_mfma_f32_16x16x32_bf16(ah0, bh0, acc, 0, 0, 0);
            acc = __builtin_amdgcn_mfma_f32_16x16x32_bf16(ah0, bl0, acc, 0, 0, 0);
            acc = __builtin_amdgcn_mfma_f32_16x16x32_bf16(al0, bh0, acc, 0, 0, 0);
            acc = __builtin_amdgcn_mfma_f32_16x16x32_bf16(ah1, bh1, acc, 0, 0, 0);
            acc = __builtin_amdgcn_mfma_f32_16x16x32_bf16(ah1, bl1, acc, 0, 0, 0);
            acc = __builtin_amdgcn_mfma_f32_16x16x32_bf16(al1, bh1, acc, 0, 0, 0);
            const float sc = s2c[o], bi = b2c[o];
            float m = -FLT_MAX;
#pragma unroll
            for (int r = 0; r < 4; ++r)
                m = fmaxf(m, fmaxf(acc[r] * sc + bi, 0.f));
            u16 h, l; split2(m, h, l);
            const int frow = wu * 4 + q;
            finh[frow * 72 + o] = h;
            finl[frow * 72 + o] = l;
        }
    }
    __syncthreads();

    {
        short8 a_hi[2], a_lo[2];
#pragma unroll
        for (int ks = 0; ks < 2; ++ks) {
            a_hi[ks] = *(const short8*)&finh[j * 72 + q * 8 + ks * 32];
            a_lo[ks] = *(const short8*)&finl[j * 72 + q * 8 + ks * 32];
        }
        float p[3][4];
#pragma unroll
        for (int oo = 0; oo < 3; ++oo)
#pragma unroll
            for (int r = 0; r < 4; ++r) p[oo][r] = 0.f;

#pragma unroll
        for (int ci = 0; ci < 4; ++ci) {
            const int o = (wu * 4 + ci) * 16 + j;
            const u16* wr_h = w4ah + (size_t)o * 192 + q * 8;
            const u16* wr_l = w4al + (size_t)o * 192 + q * 8;
            f32x4 acc = (f32x4){0.f, 0.f, 0.f, 0.f};
#pragma unroll
            for (int ks = 0; ks < 2; ++ks) {
                short8 bh = *(const short8*)(wr_h + ks * 32);
                short8 bl = *(const short8*)(wr_l + ks * 32);
                acc = __builtin_amdgcn_mfma_f32_16x16x32_bf16(a_hi[ks], bh, acc, 0, 0, 0);
                acc = __builtin_amdgcn_mfma_f32_16x16x32_bf16(a_hi[ks], bl, acc, 0, 0, 0);
                acc = __builtin_amdgcn_mfma_f32_16x16x32_bf16(a_lo[ks], bh, acc, 0, 0, 0);
            }
            const float bi = b4a[o] + g4[(size_t)b * 256 + o];
            float w0 = W4b[o], w1 = W4b[256 + o], w2 = W4b[512 + o];
#pragma unroll
            for (int r = 0; r < 4; ++r) {
                float v = fmaxf(acc[r] + bi, 0.f);
                p[0][r] += w0 * v;
                p[1][r] += w1 * v;
                p[2][r] += w2 * v;
            }
        }
#pragma unroll
        for (int oo = 0; oo < 3; ++oo)
#pragma unroll
            for (int r = 0; r < 4; ++r) {
#pragma unroll
                for (int mask = 1; mask < 16; mask <<= 1)
                    p[oo][r] += __shfl_xor(p[oo][r], mask, 64);
            }
        if (j == 0) {
#pragma unroll
            for (int oo = 0; oo < 3; ++oo)
#pragma unroll
                for (int r = 0; r < 4; ++r)
                    pred[wu][oo][q * 4 + r] = p[oo][r];
        }
    }
    __syncthreads();

    if (t < 48) {
        const int oo = t >> 4, rr = t & 15;
        float s = (pred[0][oo][rr] + pred[1][oo][rr]) +
                  (pred[2][oo][rr] + pred[3][oo][rr]) + b4b[oo];
        out[((size_t)b * 3 + oo) * 2048 + n0 + rr] = s;
    }
}

extern "C" void kernel_launch(void* const* d_in, const int* in_sizes, int n_in,
                              void* d_out, int out_size, void* d_ws, size_t ws_size,
                              hipStream_t stream)
{
    const float* x     = (const float*)d_in[0];
    const float* W_dup = (const float*)d_in[1];
    const float* s_dup = (const float*)d_in[2];
    const float* b_dup = (const float*)d_in[3];
    const float* W_c1  = (const float*)d_in[4];
    const float* s_c1  = (const float*)d_in[5];
    const float* b_c1  = (const float*)d_in[6];
    const float* W2a   = (const float*)d_in[7];
    const float* s2a   = (const float*)d_in[8];
    const float* b2a   = (const float*)d_in[9];
    const float* W2b   = (const float*)d_in[10];
    const float* s2b   = (const float*)d_in[11];
    const float* b2b   = (const float*)d_in[12];
    const float* W2c   = (const float*)d_in[13];
    const float* s2c   = (const float*)d_in[14];
    const float* b2c   = (const float*)d_in[15];
    const float* W3a   = (const float*)d_in[16];
    const float* s3a   = (const float*)d_in[17];
    const float* b3a   = (const float*)d_in[18];
    const float* W3b   = (const float*)d_in[19];
    const float* s3b   = (const float*)d_in[20];
    const float* b3b   = (const float*)d_in[21];
    const float* W4a   = (const float*)d_in[22];
    const float* b4a   = (const float*)d_in[23];
    const float* W4b   = (const float*)d_in[24];
    const float* b4b   = (const float*)d_in[25];

    if (ws_size < WS_FLOATS * sizeof(float)) return;

    float* ws = (float*)d_ws;
    u16* whi   = (u16*)(ws + OFF_W);
    u16* wlo   = whi + 131072;
    u64* part  = (u64*)(ws + OFF_FEATR);
    float* y    = ws + OFF_YZ;
    float* z    = ws + OFF_Zf;
    u16* h2thi = (u16*)(ws + OFF_FIN);
    u16* h2tlo = h2thi + 1048576;
    float* xxb  = ws + OFF_XX;
    float* gp   = ws + OFF_G;
    float* g4   = ws + OFF_G4;
    float* out  = (float*)d_out;

    // 0) prep: weight split only
    prep<<<416, 256, 0, stream>>>(W_dup, W_c1, W2a, W2b, W2c, W4a, whi, wlo);
    // 1) backbone (absorbs x transpose): conv1 -> h2(+xx,+gmax) -> y,z
    backbone<<<dim3(64, 8), 512, 0, stream>>>(
        x, whi, wlo, s_dup, b_dup, s_c1, b_c1,
        h2thi, h2tlo, xxb, gp, y, z);
    // 2) kNN (r9 config) + gconv strip (z==8)
    knn_gconv<<<dim3(32, 2, 9), 256, 0, stream>>>(
        h2thi, h2tlo, xxb, part,
        gp, W3a, s3a, b3a, W3b, s3b, b3b, W4a, g4);
    // 3) fused merge+feat2a+conv2b+conv2c+maxk+h4+projection -> out
    fused_edge<<<1024, 256, 0, stream>>>(
        part, y, z, s2a, b2a,
        whi + WO_2B, wlo + WO_2B, s2b, b2b,
        whi + WO_2C, wlo + WO_2C, s2c, b2c,
        whi + WO_4A, wlo + WO_4A, b4a, g4, W4b, b4b, out);
}